// Round 3
// baseline (237.055 us; speedup 1.0000x reference)
//
#include <hip/hip_runtime.h>
#include <hip/hip_bf16.h>

// Problem constants (from reference)
#define N_NODES 100000
#define FEAT    256
#define HID     128
#define REL     2
#define BATCH   20000
#define KNEI    10

#define APAD    8            // pad shorts per LDS A row (breaks pow-2 stride)
#define AROW    (768 + APAD) // 776 shorts = 1552 B row stride

typedef short bf16x8 __attribute__((ext_vector_type(8)));
typedef float f32x4  __attribute__((ext_vector_type(4)));

__device__ __forceinline__ unsigned short f2bf(float x) {
    union { float f; unsigned u; } v; v.f = x;
    unsigned r = v.u + 0x7fffu + ((v.u >> 16) & 1u);   // RNE
    return (unsigned short)(r >> 16);
}

__device__ __forceinline__ float bf2f(unsigned short s) {
    union { unsigned u; float f; } v; v.u = ((unsigned)s) << 16;
    return v.f;
}

__device__ __forceinline__ ushort4 pack4(float a, float b, float c, float d) {
    ushort4 p; p.x = f2bf(a); p.y = f2bf(b); p.z = f2bf(c); p.w = f2bf(d);
    return p;
}

// Swizzled B index for logical (k, n):
//   kt=k>>5, j=k&7, hi=(k>>3)&3, lane=hi*16+(n&15), nt=n>>4
//   dest = ((kt*8+nt)*64 + lane)*8 + j
__device__ __forceinline__ size_t bsw_index(int k, int n) {
    int kt = k >> 5, j = k & 7, hi = (k >> 3) & 3;
    int lane = hi * 16 + (n & 15), nt = n >> 4;
    return ((size_t)(kt * 8 + nt) * 64 + lane) * 8 + j;
}

// ---------------------------------------------------------------------------
// to_bf16: stream-convert features fp32 -> bf16 table (102 MB read, 51 MB write)
// ---------------------------------------------------------------------------
__global__ __launch_bounds__(256) void to_bf16(const float* __restrict__ f,
                                               unsigned short* __restrict__ o,
                                               int n4) {
    const int stride = gridDim.x * 256;
    for (int i = blockIdx.x * 256 + threadIdx.x; i < n4; i += stride) {
        float4 v = ((const float4*)f)[i];
        ((ushort4*)o)[i] = pack4(v.x, v.y, v.z, v.w);
    }
}

// ---------------------------------------------------------------------------
// prep_B: build collapsed weight into MFMA-swizzled bf16 layout.
// blocks 0..31  : Wcat[256+rel*256+f][n] = dot(W_stc[rel][f][:], W_det[256+rel*128...][n])
// blocks 32..33 : straight copy of W_det rows 0..255 (coalesced reads)
// ---------------------------------------------------------------------------
__global__ __launch_bounds__(256) void prep_B(const float* __restrict__ W_stc,
                                              const float* __restrict__ W_det,
                                              unsigned short* __restrict__ Bsw) {
    const int blk = blockIdx.x;
    const int tid = threadIdx.x;
    if (blk < 32) {
        const int rel   = blk >> 4;
        const int fbase = (blk & 15) * 16;
        const int n     = tid & 127;
        const int fh    = tid >> 7;              // 0..1
        const float* wd = W_det + (size_t)(256 + rel * HID) * HID + n;  // column base
        #pragma unroll
        for (int fo = 0; fo < 8; ++fo) {
            const int f = fbase + fh * 8 + fo;
            const float* ws = W_stc + (size_t)(rel * FEAT + f) * HID;
            float acc = 0.f;
            #pragma unroll 8
            for (int j2 = 0; j2 < HID; ++j2) acc += ws[j2] * wd[(size_t)j2 * HID];
            const int k = 256 + rel * 256 + f;
            Bsw[bsw_index(k, n)] = f2bf(acc);
        }
    } else {
        const int base = (blk - 32) * 16384;     // 2 blocks x 16384 elems
        #pragma unroll 4
        for (int i = 0; i < 64; ++i) {
            const int idx = base + i * 256 + tid;  // < 32768
            const int k = idx >> 7, n = idx & 127;
            Bsw[bsw_index(k, n)] = f2bf(W_det[idx]);
        }
    }
}

// ---------------------------------------------------------------------------
// fused: gather+mean into LDS A-tile (bf16), then MFMA GEMM + ReLU.
// One block (4 waves) per 16-row M-tile. 1250 blocks.
// BF16 path: table is the 51 MB bf16 feature table, 8B/lane row reads.
// ---------------------------------------------------------------------------
template<bool BF16>
__global__ __launch_bounds__(256, 4) void fused_k(const int* __restrict__ nodes,
                                                  const int* __restrict__ neigh_idx,
                                                  const void* __restrict__ table,
                                                  const unsigned short* __restrict__ Bsw,
                                                  float* __restrict__ out) {
    __shared__ unsigned short As[16 * AROW];   // 24832 B

    const int blk  = blockIdx.x;               // m-tile id (0..1249)
    const int w    = threadIdx.x >> 6;         // wave 0..3
    const int lane = threadIdx.x & 63;
    const float inv = 1.0f / (float)KNEI;

    // ---- Phase 1: gather + mean ----
    #pragma unroll
    for (int e = 0; e < 4; ++e) {
        const int m = w * 4 + e;               // row in tile
        const int b = blk * 16 + m;            // batch element
        const int self = nodes[b];
        const int* i0 = neigh_idx + (size_t)b * KNEI;
        const int* i1 = neigh_idx + (size_t)(BATCH + b) * KNEI;
        ushort4* row = (ushort4*)(As + m * AROW);

        if constexpr (BF16) {
            const ushort4* F = (const ushort4*)table;   // 64 ushort4 per row
            ushort4 sf = F[(size_t)self * 64 + lane];
            float4 s0 = make_float4(0.f, 0.f, 0.f, 0.f);
            float4 s1 = make_float4(0.f, 0.f, 0.f, 0.f);
            #pragma unroll
            for (int k = 0; k < KNEI; ++k) {
                ushort4 v = F[(size_t)i0[k] * 64 + lane];
                s0.x += bf2f(v.x); s0.y += bf2f(v.y); s0.z += bf2f(v.z); s0.w += bf2f(v.w);
            }
            #pragma unroll
            for (int k = 0; k < KNEI; ++k) {
                ushort4 v = F[(size_t)i1[k] * 64 + lane];
                s1.x += bf2f(v.x); s1.y += bf2f(v.y); s1.z += bf2f(v.z); s1.w += bf2f(v.w);
            }
            row[lane]       = sf;   // already bf16
            row[64 + lane]  = pack4(s0.x * inv, s0.y * inv, s0.z * inv, s0.w * inv);
            row[128 + lane] = pack4(s1.x * inv, s1.y * inv, s1.z * inv, s1.w * inv);
        } else {
            const float4* F4 = (const float4*)table;
            float4 sf = F4[(size_t)self * 64 + lane];
            float4 s0 = make_float4(0.f, 0.f, 0.f, 0.f);
            float4 s1 = make_float4(0.f, 0.f, 0.f, 0.f);
            #pragma unroll
            for (int k = 0; k < KNEI; ++k) {
                float4 v = F4[(size_t)i0[k] * 64 + lane];
                s0.x += v.x; s0.y += v.y; s0.z += v.z; s0.w += v.w;
            }
            #pragma unroll
            for (int k = 0; k < KNEI; ++k) {
                float4 v = F4[(size_t)i1[k] * 64 + lane];
                s1.x += v.x; s1.y += v.y; s1.z += v.z; s1.w += v.w;
            }
            row[lane]       = pack4(sf.x, sf.y, sf.z, sf.w);
            row[64 + lane]  = pack4(s0.x * inv, s0.y * inv, s0.z * inv, s0.w * inv);
            row[128 + lane] = pack4(s1.x * inv, s1.y * inv, s1.z * inv, s1.w * inv);
        }
    }
    __syncthreads();

    // ---- Phase 2: GEMM + ReLU ----
    const int quad = lane >> 4;
    const int l16  = lane & 15;
    const unsigned short* a_base = As + l16 * AROW + quad * 8;

    f32x4 acc0 = (f32x4){0.f, 0.f, 0.f, 0.f};
    f32x4 acc1 = (f32x4){0.f, 0.f, 0.f, 0.f};
    const int nt0 = w, nt1 = w + 4;

    #pragma unroll
    for (int kt = 0; kt < 24; ++kt) {
        bf16x8 a = *(const bf16x8*)(a_base + kt * 32);
        const unsigned short* bk = Bsw + ((size_t)(kt * 8) * 64 + lane) * 8;
        bf16x8 b0 = *(const bf16x8*)(bk + (size_t)nt0 * 64 * 8);
        bf16x8 b1 = *(const bf16x8*)(bk + (size_t)nt1 * 64 * 8);
        acc0 = __builtin_amdgcn_mfma_f32_16x16x32_bf16(a, b0, acc0, 0, 0, 0);
        acc1 = __builtin_amdgcn_mfma_f32_16x16x32_bf16(a, b1, acc1, 0, 0, 0);
    }

    float* orow = out + (size_t)(blk * 16) * HID;
    #pragma unroll
    for (int r = 0; r < 4; ++r) {
        const int row = quad * 4 + r;
        float v0 = acc0[r];
        float v1 = acc1[r];
        orow[(size_t)row * HID + nt0 * 16 + l16] = v0 > 0.f ? v0 : 0.f;
        orow[(size_t)row * HID + nt1 * 16 + l16] = v1 > 0.f ? v1 : 0.f;
    }
}

extern "C" void kernel_launch(void* const* d_in, const int* in_sizes, int n_in,
                              void* d_out, int out_size, void* d_ws, size_t ws_size,
                              hipStream_t stream) {
    const int*   nodes     = (const int*)d_in[0];
    const int*   neigh_idx = (const int*)d_in[1];
    const float* features  = (const float*)d_in[2];
    const float* W_stc     = (const float*)d_in[3];
    const float* W_det     = (const float*)d_in[4];
    float* out = (float*)d_out;

    unsigned short* Bsw = (unsigned short*)d_ws;                        // 192 KB
    unsigned short* Fbf = (unsigned short*)((char*)d_ws + 256 * 1024);  // 51.2 MB

    const size_t need = 256 * 1024 + (size_t)N_NODES * FEAT * 2;
    const bool bf16path = ws_size >= need;

    if (bf16path)
        to_bf16<<<2048, 256, 0, stream>>>(features, Fbf, N_NODES * FEAT / 4);
    prep_B<<<34, 256, 0, stream>>>(W_stc, W_det, Bsw);
    if (bf16path)
        fused_k<true><<<BATCH / 16, 256, 0, stream>>>(nodes, neigh_idx, Fbf, Bsw, out);
    else
        fused_k<false><<<BATCH / 16, 256, 0, stream>>>(nodes, neigh_idx, features, Bsw, out);
}